// Round 14
// baseline (230.987 us; speedup 1.0000x reference)
//
#include <hip/hip_runtime.h>

#define HID 1024
#define SEQ 2048
#define NB 4
#define BS 8192  // NB*SEQ

typedef __attribute__((ext_vector_type(8))) short short8;
typedef __attribute__((ext_vector_type(8))) unsigned short ushort8;
typedef __attribute__((ext_vector_type(4))) float f32x4;

__device__ __forceinline__ float bf2f(unsigned short u) {
  unsigned int x = ((unsigned int)u) << 16;
  return __builtin_bit_cast(float, x);
}
__device__ __forceinline__ unsigned short f2bf(float f) {
  unsigned int x = __builtin_bit_cast(unsigned int, f);
  x = x + 0x7fffu + ((x >> 16) & 1u);
  return (unsigned short)(x >> 16);
}

#define GLOAD16(g, l)                                                          \
  __builtin_amdgcn_global_load_lds(                                            \
      (const __attribute__((address_space(1))) unsigned int*)(g),              \
      (__attribute__((address_space(3))) unsigned int*)(l), 16, 0, 0)

// ---------------- fp32 -> bf16 cast, 8 elems/thread ----------------
__global__ void cast_f32_to_bf16(const float* __restrict__ in,
                                 unsigned short* __restrict__ out, int n) {
  int i = (blockIdx.x * 256 + threadIdx.x) * 8;
  if (i >= n) return;
  f32x4 a = *(const f32x4*)(in + i);
  f32x4 b = *(const f32x4*)(in + i + 4);
  ushort8 o;
  o[0] = f2bf(a[0]); o[1] = f2bf(a[1]); o[2] = f2bf(a[2]); o[3] = f2bf(a[3]);
  o[4] = f2bf(b[0]); o[5] = f2bf(b[1]); o[6] = f2bf(b[2]); o[7] = f2bf(b[3]);
  *(ushort8*)(out + i) = o;
}

// ------------- 1024x1024 fp32 -> bf16 transposed cast -------------
__global__ __launch_bounds__(256) void transpose_cast(
    const float* __restrict__ in, unsigned short* __restrict__ out) {
  __shared__ float t[32][33];
  const int bx = blockIdx.x * 32, by = blockIdx.y * 32;
  const int tx = threadIdx.x & 31, ty = threadIdx.x >> 5;  // 32 x 8
#pragma unroll
  for (int i = 0; i < 4; ++i)
    t[ty + i * 8][tx] = in[(by + ty + i * 8) * 1024 + bx + tx];
  __syncthreads();
#pragma unroll
  for (int i = 0; i < 4; ++i)
    out[(bx + ty + i * 8) * 1024 + by + tx] = f2bf(t[tx][ty + i * 8]);
}

// ------------- b'[h] = bo[h] + sum_k Wo[h,k] * bv[k] -------------
__global__ __launch_bounds__(256) void bias_fuse(const float* __restrict__ Wo,
                                                 const float* __restrict__ bv,
                                                 const float* __restrict__ bo,
                                                 float* __restrict__ bp) {
  const int row = blockIdx.x * 4 + (threadIdx.x >> 6);
  const int lane = threadIdx.x & 63;
  float s = 0.f;
  for (int k = lane; k < 1024; k += 64) s += Wo[row * 1024 + k] * bv[k];
#pragma unroll
  for (int off = 32; off >= 1; off >>= 1) s += __shfl_xor(s, off, 64);
  if (lane == 0) bp[row] = s + bo[row];
}

// ========== 256x128 NT GEMM, BK=32, 8 waves, 2 blocks/CU ===================
// C[m,n] = alpha * sum_k A[m,k]*B[n,k] (+bias). 512 thr = 8 waves (4Mx2N),
// 64x64 per wave. 48KB LDS double-buffered + launch_bounds(512,4) ->
// 2 resident blocks/CU: cross-block TLP covers the vmcnt/barrier drain
// (the only lever that has moved per-dispatch time, r6 vs r12/r13).
// T3-minimal loop; round-7-verified 0-conflict swizzle (16B-slot ^= row
// bits 1-2; inverse-swizzled global source, XOR'd ds_read slot - rule 21);
// rule-18 lgkmcnt(0)+sched_barrier batch before the MFMA cluster.
// BIAS_MODE: 0 none, 1 bias[col], 3 col<1024?bias:bias2.
// EPI: 0 plain, 1 exp(v)+rowsum->Srow atomics, 2 scale by 1/Srow (pre-bias).
template <int OUT_F32, int BIAS_MODE, int EPI>
__global__ __launch_bounds__(512, 4) void gemm_s(
    const unsigned short* __restrict__ A, const unsigned short* __restrict__ B,
    void* __restrict__ Cv, const float* __restrict__ bias,
    const float* __restrict__ bias2, float* __restrict__ Srow, int K, int lda,
    int ldb, int ldc, long long bsA, long long bsB, long long bsC,
    float alpha) {
  __shared__ unsigned short lA[2][256 * 32];  // 32 KB
  __shared__ unsigned short lB[2][128 * 32];  // 16 KB

  const int tid = threadIdx.x;
  const int lane = tid & 63, wid = tid >> 6;
  const int fr = lane & 15, fq = lane >> 4;
  const int wm = wid >> 1, wn = wid & 1;  // 4M x 2N waves

  // XCD-aware chunked swizzle on flattened (y,x); all grids have nwg%8==0.
  const int nx = gridDim.x;
  const int nwg = nx * gridDim.y;
  int f = blockIdx.y * nx + blockIdx.x;
  f = (f & 7) * (nwg >> 3) + (f >> 3);
  const int bx = f % nx, by = f / nx;
  const int bz = blockIdx.z;

  const unsigned short* Ag = A + bz * bsA + (long long)by * 256 * lda;
  const unsigned short* Bg = B + bz * bsB + (long long)bx * 128 * ldb;
  const int NT = K >> 5;

  // Staging: LDS dest linear (wave-uniform base + lane*16B). Global source
  // column pre-swizzled: phys slot (tid&3) holds logical (tid&3)^((row>>1)&3).
  const int srow = tid >> 2;                            // 0..127
  const int scol = 8 * ((tid & 3) ^ ((tid >> 3) & 3));  // swizzled 16B slot
  const int ldst = wid * 512;                           // ushorts, uniform

  auto stage = [&](int t) {
    const int b = t & 1;
    GLOAD16(Ag + (long long)srow * lda + t * 32 + scol, &lA[b][ldst]);
    GLOAD16(Ag + (long long)(128 + srow) * lda + t * 32 + scol,
            &lA[b][4096 + ldst]);
    GLOAD16(Bg + (long long)srow * ldb + t * 32 + scol, &lB[b][ldst]);
  };

  // ds_read offsets: XOR the 16B-slot with row bits 1-2 (= fr bits 1-2).
  const int xm = ((fr >> 1) & 3) << 3;  // ushort-unit mask (bits 3-4)

  f32x4 acc[4][4] = {};

  stage(0);
  asm volatile("s_waitcnt vmcnt(0)" ::: "memory");
  __builtin_amdgcn_s_barrier();

  for (int t = 0; t < NT; ++t) {
    if (t + 1 < NT) stage(t + 1);  // issue BEFORE compute (T3 recipe)
    const unsigned short* pa = lA[t & 1];
    const unsigned short* pb = lB[t & 1];
    short8 av[4], bw[4];
#pragma unroll
    for (int i = 0; i < 4; ++i)
      av[i] = *(const short8*)(pa +
                               (((wm * 64 + i * 16 + fr) * 32 + fq * 8) ^ xm));
#pragma unroll
    for (int n = 0; n < 4; ++n)
      bw[n] = *(const short8*)(pb +
                               (((wn * 64 + n * 16 + fr) * 32 + fq * 8) ^ xm));
    asm volatile("s_waitcnt lgkmcnt(0)" ::: "memory");
    __builtin_amdgcn_sched_barrier(0);
    __builtin_amdgcn_s_setprio(1);
#pragma unroll
    for (int i = 0; i < 4; ++i)
#pragma unroll
      for (int n = 0; n < 4; ++n)
        acc[i][n] = __builtin_amdgcn_mfma_f32_16x16x32_bf16(av[i], bw[n],
                                                            acc[i][n], 0, 0, 0);
    __builtin_amdgcn_s_setprio(0);
    asm volatile("s_waitcnt vmcnt(0)" ::: "memory");  // next tile landed
    __builtin_amdgcn_s_barrier();
  }

  // Epilogue. C/D frag layout: col = 16*frag + fr, row = fq*4 + j.
  const long long cb0 = (long long)bz * bsC;
  float* sredf = (float*)lA;  // [256][2] row-sum scratch (EPI==1)
#pragma unroll
  for (int i = 0; i < 4; ++i)
#pragma unroll
    for (int j = 0; j < 4; ++j) {
      const int row = wm * 64 + i * 16 + fq * 4 + j;
      float inv = 1.0f;
      if (EPI == 2) inv = 1.0f / Srow[(long long)bz * SEQ + by * 256 + row];
      float rps = 0.0f;
#pragma unroll
      for (int n = 0; n < 4; ++n) {
        const int col = bx * 128 + wn * 64 + n * 16 + fr;
        float v = acc[i][n][j] * alpha;
        if (EPI == 1) { v = __expf(v); rps += v; }
        if (EPI == 2) v *= inv;
        if (BIAS_MODE == 1) v += bias[col];
        if (BIAS_MODE == 3) v += (col < 1024) ? bias[col] : bias2[col - 1024];
        const long long idx = cb0 + (long long)(by * 256 + row) * ldc + col;
        if (OUT_F32)
          ((float*)Cv)[idx] = v;
        else
          ((unsigned short*)Cv)[idx] = f2bf(v);
      }
      if (EPI == 1) {
        rps += __shfl_xor(rps, 1, 64);
        rps += __shfl_xor(rps, 2, 64);
        rps += __shfl_xor(rps, 4, 64);
        rps += __shfl_xor(rps, 8, 64);
        if (fr == 0) sredf[row * 2 + wn] = rps;
      }
    }
  if (EPI == 1) {
    __syncthreads();
    if (tid < 256) {
      const float s2 = sredf[tid * 2] + sredf[tid * 2 + 1];
      atomicAdd(Srow + (long long)bz * SEQ + by * 256 + tid, s2);
    }
  }
}

extern "C" void kernel_launch(void* const* d_in, const int* in_sizes, int n_in,
                              void* d_out, int out_size, void* d_ws,
                              size_t ws_size, hipStream_t stream) {
  (void)in_sizes; (void)n_in; (void)out_size; (void)ws_size;
  const float* x = (const float*)d_in[0];
  const float* Wq = (const float*)d_in[1];
  const float* bq = (const float*)d_in[2];
  const float* Wk = (const float*)d_in[3];
  const float* bk = (const float*)d_in[4];
  const float* Wv = (const float*)d_in[5];
  const float* bv = (const float*)d_in[6];
  const float* Wo = (const float*)d_in[7];
  const float* bo = (const float*)d_in[8];
  float* out = (float*)d_out;

  char* ws = (char*)d_ws;
  unsigned short* xbf  = (unsigned short*)(ws + 0);         // 16 MiB
  unsigned short* wqk  = (unsigned short*)(ws + 16777216);  // 4 MiB [2048][1024]
  unsigned short* wobf = (unsigned short*)(ws + 20971520);  // 2 MiB
  unsigned short* wvT  = (unsigned short*)(ws + 23068672);  // 2 MiB (Wv^T)
  unsigned short* wov  = (unsigned short*)(ws + 25165824);  // 2 MiB (Wo.Wv)
  float*          bpr  = (float*)        (ws + 27262976);   // 4 KiB (Wo.bv+bo)
  float*          Srow = (float*)        (ws + 28311552);   // 32 KiB rowsums
  unsigned short* VWoT = (unsigned short*)(ws + 33554432);  // 16 MiB [1024][8192]
  unsigned short* QKb  = (unsigned short*)(ws + 50331648);  // 32 MiB [8192][2048]
  unsigned short* P    = (unsigned short*)(ws + 83886080);  // 32 MiB [4][2048][2048]

  // casts & small precomputes (round-12 dataflow, best measured total)
  cast_f32_to_bf16<<<4096, 256, 0, stream>>>(x, xbf, BS * HID);
  cast_f32_to_bf16<<<512, 256, 0, stream>>>(Wq, wqk, HID * HID);
  cast_f32_to_bf16<<<512, 256, 0, stream>>>(Wk, wqk + HID * HID, HID * HID);
  cast_f32_to_bf16<<<512, 256, 0, stream>>>(Wo, wobf, HID * HID);
  transpose_cast<<<dim3(32, 32), 256, 0, stream>>>(Wv, wvT);
  bias_fuse<<<256, 256, 0, stream>>>(Wo, bv, bo, bpr);
  hipMemsetAsync(Srow, 0, NB * SEQ * sizeof(float), stream);

  // wov[h,k] = sum_j Wo[h,j] Wv[j,k] = NT(wobf, wvT) : [1024,1024]
  gemm_s<0, 0, 0><<<dim3(8, 4, 1), 512, 0, stream>>>(
      wobf, wvT, wov, nullptr, nullptr, nullptr, HID, HID, HID, HID, 0, 0, 0,
      1.0f);
  // VWoT[h,s] = sum_k wov[h,k] x[s,k] = NT(wov, xbf) : [1024,8192]
  gemm_s<0, 0, 0><<<dim3(64, 4, 1), 512, 0, stream>>>(
      wov, xbf, VWoT, nullptr, nullptr, nullptr, HID, HID, HID, BS, 0, 0, 0,
      1.0f);
  // [Q|K] = x @ [Wq;Wk]^T + [bq;bk] : [8192,2048]
  gemm_s<0, 3, 0><<<dim3(16, 32, 1), 512, 0, stream>>>(
      xbf, wqk, QKb, bq, bk, nullptr, HID, HID, HID, 2048, 0, 0, 0, 1.0f);
  // P = exp(Q @ K^T / 32) per batch + rowsums : [4][2048][2048]
  gemm_s<0, 0, 1><<<dim3(16, 8, NB), 512, 0, stream>>>(
      QKb, QKb + 1024, P, nullptr, nullptr, Srow, HID, 2048, 2048, SEQ,
      (long long)SEQ * 2048, (long long)SEQ * 2048, (long long)SEQ * SEQ,
      0.03125f);
  // out = (P @ VWoT^T) / Srow + b' : [8192,1024] fp32 (k-window via bsB)
  gemm_s<1, 1, 2><<<dim3(8, 8, NB), 512, 0, stream>>>(
      P, VWoT, out, bpr, nullptr, Srow, SEQ, SEQ, BS, HID,
      (long long)SEQ * SEQ, (long long)SEQ, (long long)SEQ * HID, 1.0f);
}

// Round 15
// 224.034 us; speedup vs baseline: 1.0310x; 1.0310x over previous
//
#include <hip/hip_runtime.h>

#define HID 1024
#define SEQ 2048
#define NB 4
#define BS 8192  // NB*SEQ

typedef __attribute__((ext_vector_type(8))) short short8;
typedef __attribute__((ext_vector_type(8))) unsigned short ushort8;
typedef __attribute__((ext_vector_type(4))) float f32x4;

__device__ __forceinline__ float bf2f(unsigned short u) {
  unsigned int x = ((unsigned int)u) << 16;
  return __builtin_bit_cast(float, x);
}
__device__ __forceinline__ unsigned short f2bf(float f) {
  unsigned int x = __builtin_bit_cast(unsigned int, f);
  x = x + 0x7fffu + ((x >> 16) & 1u);
  return (unsigned short)(x >> 16);
}

#define GLOAD16(g, l)                                                          \
  __builtin_amdgcn_global_load_lds(                                            \
      (const __attribute__((address_space(1))) unsigned int*)(g),              \
      (__attribute__((address_space(3))) unsigned int*)(l), 16, 0, 0)

// ---------------- fp32 -> bf16 cast, 8 elems/thread ----------------
__global__ void cast_f32_to_bf16(const float* __restrict__ in,
                                 unsigned short* __restrict__ out, int n) {
  int i = (blockIdx.x * 256 + threadIdx.x) * 8;
  if (i >= n) return;
  f32x4 a = *(const f32x4*)(in + i);
  f32x4 b = *(const f32x4*)(in + i + 4);
  ushort8 o;
  o[0] = f2bf(a[0]); o[1] = f2bf(a[1]); o[2] = f2bf(a[2]); o[3] = f2bf(a[3]);
  o[4] = f2bf(b[0]); o[5] = f2bf(b[1]); o[6] = f2bf(b[2]); o[7] = f2bf(b[3]);
  *(ushort8*)(out + i) = o;
}

// ------------- 1024x1024 fp32 -> bf16 transposed cast -------------
__global__ __launch_bounds__(256) void transpose_cast(
    const float* __restrict__ in, unsigned short* __restrict__ out) {
  __shared__ float t[32][33];
  const int bx = blockIdx.x * 32, by = blockIdx.y * 32;
  const int tx = threadIdx.x & 31, ty = threadIdx.x >> 5;  // 32 x 8
#pragma unroll
  for (int i = 0; i < 4; ++i)
    t[ty + i * 8][tx] = in[(by + ty + i * 8) * 1024 + bx + tx];
  __syncthreads();
#pragma unroll
  for (int i = 0; i < 4; ++i)
    out[(bx + ty + i * 8) * 1024 + by + tx] = f2bf(t[tx][ty + i * 8]);
}

// ------------- b'[h] = bo[h] + sum_k Wo[h,k] * bv[k] -------------
__global__ __launch_bounds__(256) void bias_fuse(const float* __restrict__ Wo,
                                                 const float* __restrict__ bv,
                                                 const float* __restrict__ bo,
                                                 float* __restrict__ bp) {
  const int row = blockIdx.x * 4 + (threadIdx.x >> 6);
  const int lane = threadIdx.x & 63;
  float s = 0.f;
  for (int k = lane; k < 1024; k += 64) s += Wo[row * 1024 + k] * bv[k];
#pragma unroll
  for (int off = 32; off >= 1; off >>= 1) s += __shfl_xor(s, off, 64);
  if (lane == 0) bp[row] = s + bo[row];
}

// ========== 256 x BN 2-phase NT GEMM (BK=64, 8 waves) — r12 engine =========
// Best engine for K=1024 dispatches (fewer, fatter iterations). See r12.
// BIAS_MODE: 0 none, 1 bias[col], 3 col<1024?bias:bias2.
template <int BN, int OUT_F32, int BIAS_MODE>
__global__ __launch_bounds__(512, 2) void gemm2p(
    const unsigned short* __restrict__ A, const unsigned short* __restrict__ B,
    void* __restrict__ Cv, const float* __restrict__ bias,
    const float* __restrict__ bias2, int K, int lda, int ldb, int ldc,
    long long bsA, long long bsB, long long bsC, float alpha) {
  static_assert(BN == 256 || BN == 128, "BN");
  constexpr int WMW = (BN == 256) ? 2 : 4;
  constexpr int WNW = 8 / WMW;
  constexpr int MI = (256 / WMW) / 16;
  constexpr int GB = BN / 64;
  constexpr int WROWS = 256 / WMW;

  __shared__ unsigned short lA[2][256 * 64];  // 64 KB
  __shared__ unsigned short lB[2][BN * 64];   // 64 or 32 KB

  const int tid = threadIdx.x;
  const int lane = tid & 63, wid = tid >> 6;
  const int fr = lane & 15, fq = lane >> 4;
  const int wm = wid / WNW, wn = wid % WNW;

  const int nx = gridDim.x;
  const int nwg = nx * gridDim.y;
  int f = blockIdx.y * nx + blockIdx.x;
  f = (f & 7) * (nwg >> 3) + (f >> 3);
  const int bx = f % nx, by = f / nx;
  const int bz = blockIdx.z;

  const unsigned short* Ag = A + bz * bsA + (long long)by * 256 * lda;
  const unsigned short* Bg = B + bz * bsB + (long long)bx * BN * ldb;
  const int NT = K >> 6;

  const int srow = tid >> 3;
  const int gcol = 8 * ((tid & 7) ^ ((tid >> 3) & 7));
  const int ldst = wid * 512;

  auto stage = [&](int t) {
    const int b = t & 1;
#pragma unroll
    for (int c = 0; c < 4; ++c)
      GLOAD16(Ag + (long long)(c * 64 + srow) * lda + t * 64 + gcol,
              &lA[b][c * 4096 + ldst]);
#pragma unroll
    for (int c = 0; c < GB; ++c)
      GLOAD16(Bg + (long long)(c * 64 + srow) * ldb + t * 64 + gcol,
              &lB[b][c * 4096 + ldst]);
  };

  const int rxor = fr & 7;
  f32x4 acc[MI][4] = {};

  auto phase = [&](const unsigned short* pa, const unsigned short* pb,
                   int kk) {
    short8 av[MI], bw[4];
    const int slot = ((kk << 2) | fq) ^ rxor;
#pragma unroll
    for (int i = 0; i < MI; ++i)
      av[i] = *(const short8*)(pa + (wm * WROWS + i * 16 + fr) * 64 + slot * 8);
#pragma unroll
    for (int n = 0; n < 4; ++n)
      bw[n] = *(const short8*)(pb + (wn * 64 + n * 16 + fr) * 64 + slot * 8);
    asm volatile("s_waitcnt lgkmcnt(0)" ::: "memory");
    __builtin_amdgcn_sched_barrier(0);
    __builtin_amdgcn_s_setprio(1);
#pragma unroll
    for (int i = 0; i < MI; ++i)
#pragma unroll
      for (int n = 0; n < 4; ++n)
        acc[i][n] = __builtin_amdgcn_mfma_f32_16x16x32_bf16(av[i], bw[n],
                                                            acc[i][n], 0, 0, 0);
    __builtin_amdgcn_s_setprio(0);
  };

  stage(0);
  asm volatile("s_waitcnt vmcnt(0)" ::: "memory");
  __builtin_amdgcn_s_barrier();

  for (int t = 0; t < NT; ++t) {
    if (t + 1 < NT) stage(t + 1);
    const unsigned short* pa = lA[t & 1];
    const unsigned short* pb = lB[t & 1];
    phase(pa, pb, 0);
    phase(pa, pb, 1);
    asm volatile("s_waitcnt vmcnt(0)" ::: "memory");
    __builtin_amdgcn_s_barrier();
  }

  const long long cb0 = (long long)bz * bsC;
#pragma unroll
  for (int i = 0; i < MI; ++i)
#pragma unroll
    for (int j = 0; j < 4; ++j) {
      const int row = wm * WROWS + i * 16 + fq * 4 + j;
#pragma unroll
      for (int n = 0; n < 4; ++n) {
        const int col = bx * BN + wn * 64 + n * 16 + fr;
        float v = acc[i][n][j] * alpha;
        if (BIAS_MODE == 1) v += bias[col];
        if (BIAS_MODE == 3) v += (col < 1024) ? bias[col] : bias2[col - 1024];
        const long long idx = cb0 + (long long)(by * 256 + row) * ldc + col;
        if (OUT_F32)
          ((float*)Cv)[idx] = v;
        else
          ((unsigned short*)Cv)[idx] = f2bf(v);
      }
    }
}

// ========== 256x128 NT GEMM, BK=32, 8 waves, 2 blocks/CU — r14 engine ======
// Best engine for the K=2048 dispatches (QKT, PV): TLP covers the drain.
// BIAS_MODE: 0 none, 1 bias[col].
// EPI: 0 plain, 1 exp(v)+rowsum->Srow atomics, 2 scale by 1/Srow (pre-bias).
template <int OUT_F32, int BIAS_MODE, int EPI>
__global__ __launch_bounds__(512, 4) void gemm_s(
    const unsigned short* __restrict__ A, const unsigned short* __restrict__ B,
    void* __restrict__ Cv, const float* __restrict__ bias,
    float* __restrict__ Srow, int K, int lda, int ldb, int ldc, long long bsA,
    long long bsB, long long bsC, float alpha) {
  __shared__ unsigned short lA[2][256 * 32];  // 32 KB
  __shared__ unsigned short lB[2][128 * 32];  // 16 KB

  const int tid = threadIdx.x;
  const int lane = tid & 63, wid = tid >> 6;
  const int fr = lane & 15, fq = lane >> 4;
  const int wm = wid >> 1, wn = wid & 1;  // 4M x 2N waves

  const int nx = gridDim.x;
  const int nwg = nx * gridDim.y;
  int f = blockIdx.y * nx + blockIdx.x;
  f = (f & 7) * (nwg >> 3) + (f >> 3);
  const int bx = f % nx, by = f / nx;
  const int bz = blockIdx.z;

  const unsigned short* Ag = A + bz * bsA + (long long)by * 256 * lda;
  const unsigned short* Bg = B + bz * bsB + (long long)bx * 128 * ldb;
  const int NT = K >> 5;

  const int srow = tid >> 2;
  const int scol = 8 * ((tid & 3) ^ ((tid >> 3) & 3));
  const int ldst = wid * 512;

  auto stage = [&](int t) {
    const int b = t & 1;
    GLOAD16(Ag + (long long)srow * lda + t * 32 + scol, &lA[b][ldst]);
    GLOAD16(Ag + (long long)(128 + srow) * lda + t * 32 + scol,
            &lA[b][4096 + ldst]);
    GLOAD16(Bg + (long long)srow * ldb + t * 32 + scol, &lB[b][ldst]);
  };

  const int xm = ((fr >> 1) & 3) << 3;

  f32x4 acc[4][4] = {};

  stage(0);
  asm volatile("s_waitcnt vmcnt(0)" ::: "memory");
  __builtin_amdgcn_s_barrier();

  for (int t = 0; t < NT; ++t) {
    if (t + 1 < NT) stage(t + 1);
    const unsigned short* pa = lA[t & 1];
    const unsigned short* pb = lB[t & 1];
    short8 av[4], bw[4];
#pragma unroll
    for (int i = 0; i < 4; ++i)
      av[i] = *(const short8*)(pa +
                               (((wm * 64 + i * 16 + fr) * 32 + fq * 8) ^ xm));
#pragma unroll
    for (int n = 0; n < 4; ++n)
      bw[n] = *(const short8*)(pb +
                               (((wn * 64 + n * 16 + fr) * 32 + fq * 8) ^ xm));
    asm volatile("s_waitcnt lgkmcnt(0)" ::: "memory");
    __builtin_amdgcn_sched_barrier(0);
    __builtin_amdgcn_s_setprio(1);
#pragma unroll
    for (int i = 0; i < 4; ++i)
#pragma unroll
      for (int n = 0; n < 4; ++n)
        acc[i][n] = __builtin_amdgcn_mfma_f32_16x16x32_bf16(av[i], bw[n],
                                                            acc[i][n], 0, 0, 0);
    __builtin_amdgcn_s_setprio(0);
    asm volatile("s_waitcnt vmcnt(0)" ::: "memory");
    __builtin_amdgcn_s_barrier();
  }

  const long long cb0 = (long long)bz * bsC;
  float* sredf = (float*)lA;  // [256][2] row-sum scratch (EPI==1)
#pragma unroll
  for (int i = 0; i < 4; ++i)
#pragma unroll
    for (int j = 0; j < 4; ++j) {
      const int row = wm * 64 + i * 16 + fq * 4 + j;
      float inv = 1.0f;
      if (EPI == 2) inv = 1.0f / Srow[(long long)bz * SEQ + by * 256 + row];
      float rps = 0.0f;
#pragma unroll
      for (int n = 0; n < 4; ++n) {
        const int col = bx * 128 + wn * 64 + n * 16 + fr;
        float v = acc[i][n][j] * alpha;
        if (EPI == 1) { v = __expf(v); rps += v; }
        if (EPI == 2) v *= inv;
        if (BIAS_MODE == 1) v += bias[col];
        const long long idx = cb0 + (long long)(by * 256 + row) * ldc + col;
        if (OUT_F32)
          ((float*)Cv)[idx] = v;
        else
          ((unsigned short*)Cv)[idx] = f2bf(v);
      }
      if (EPI == 1) {
        rps += __shfl_xor(rps, 1, 64);
        rps += __shfl_xor(rps, 2, 64);
        rps += __shfl_xor(rps, 4, 64);
        rps += __shfl_xor(rps, 8, 64);
        if (fr == 0) sredf[row * 2 + wn] = rps;
      }
    }
  if (EPI == 1) {
    __syncthreads();
    if (tid < 256) {
      const float s2 = sredf[tid * 2] + sredf[tid * 2 + 1];
      atomicAdd(Srow + (long long)bz * SEQ + by * 256 + tid, s2);
    }
  }
}

extern "C" void kernel_launch(void* const* d_in, const int* in_sizes, int n_in,
                              void* d_out, int out_size, void* d_ws,
                              size_t ws_size, hipStream_t stream) {
  (void)in_sizes; (void)n_in; (void)out_size; (void)ws_size;
  const float* x = (const float*)d_in[0];
  const float* Wq = (const float*)d_in[1];
  const float* bq = (const float*)d_in[2];
  const float* Wk = (const float*)d_in[3];
  const float* bk = (const float*)d_in[4];
  const float* Wv = (const float*)d_in[5];
  const float* bv = (const float*)d_in[6];
  const float* Wo = (const float*)d_in[7];
  const float* bo = (const float*)d_in[8];
  float* out = (float*)d_out;

  char* ws = (char*)d_ws;
  unsigned short* xbf  = (unsigned short*)(ws + 0);         // 16 MiB
  unsigned short* wqk  = (unsigned short*)(ws + 16777216);  // 4 MiB [2048][1024]
  unsigned short* wobf = (unsigned short*)(ws + 20971520);  // 2 MiB
  unsigned short* wvT  = (unsigned short*)(ws + 23068672);  // 2 MiB (Wv^T)
  unsigned short* wov  = (unsigned short*)(ws + 25165824);  // 2 MiB (Wo.Wv)
  float*          bpr  = (float*)        (ws + 27262976);   // 4 KiB (Wo.bv+bo)
  float*          Srow = (float*)        (ws + 28311552);   // 32 KiB rowsums
  unsigned short* VWoT = (unsigned short*)(ws + 33554432);  // 16 MiB [1024][8192]
  unsigned short* QKb  = (unsigned short*)(ws + 50331648);  // 32 MiB [8192][2048]
  unsigned short* P    = (unsigned short*)(ws + 83886080);  // 32 MiB [4][2048][2048]

  // casts & small precomputes (r12 dataflow)
  cast_f32_to_bf16<<<4096, 256, 0, stream>>>(x, xbf, BS * HID);
  cast_f32_to_bf16<<<512, 256, 0, stream>>>(Wq, wqk, HID * HID);
  cast_f32_to_bf16<<<512, 256, 0, stream>>>(Wk, wqk + HID * HID, HID * HID);
  cast_f32_to_bf16<<<512, 256, 0, stream>>>(Wo, wobf, HID * HID);
  transpose_cast<<<dim3(32, 32), 256, 0, stream>>>(Wv, wvT);
  bias_fuse<<<256, 256, 0, stream>>>(Wo, bv, bo, bpr);
  hipMemsetAsync(Srow, 0, NB * SEQ * sizeof(float), stream);

  // wov[h,k] = sum_j Wo[h,j] Wv[j,k] = NT(wobf, wvT) : [1024,1024]
  gemm2p<128, 0, 0><<<dim3(8, 4, 1), 512, 0, stream>>>(
      wobf, wvT, wov, nullptr, nullptr, HID, HID, HID, HID, 0, 0, 0, 1.0f);
  // VWoT[h,s] = sum_k wov[h,k] x[s,k] = NT(wov, xbf) : [1024,8192]
  gemm2p<128, 0, 0><<<dim3(64, 4, 1), 512, 0, stream>>>(
      wov, xbf, VWoT, nullptr, nullptr, HID, HID, HID, BS, 0, 0, 0, 1.0f);
  // [Q|K] = x @ [Wq;Wk]^T + [bq;bk] : [8192,2048]
  gemm2p<256, 0, 3><<<dim3(8, 32, 1), 512, 0, stream>>>(
      xbf, wqk, QKb, bq, bk, HID, HID, HID, 2048, 0, 0, 0, 1.0f);
  // P = exp(Q @ K^T / 32) per batch + rowsums : [4][2048][2048] (r14 engine)
  gemm_s<0, 0, 1><<<dim3(16, 8, NB), 512, 0, stream>>>(
      QKb, QKb + 1024, P, nullptr, Srow, HID, 2048, 2048, SEQ,
      (long long)SEQ * 2048, (long long)SEQ * 2048, (long long)SEQ * SEQ,
      0.03125f);
  // out = (P @ VWoT^T) / Srow + b' : [8192,1024] fp32 (r14 engine)
  gemm_s<1, 1, 2><<<dim3(8, 8, NB), 512, 0, stream>>>(
      P, VWoT, out, bpr, Srow, SEQ, SEQ, BS, HID, (long long)SEQ * SEQ,
      (long long)SEQ, (long long)SEQ * HID, 1.0f);
}

// Round 16
// 212.932 us; speedup vs baseline: 1.0848x; 1.0521x over previous
//
#include <hip/hip_runtime.h>

#define HID 1024
#define SEQ 2048
#define NB 4
#define BS 8192  // NB*SEQ

typedef __attribute__((ext_vector_type(8))) short short8;
typedef __attribute__((ext_vector_type(8))) unsigned short ushort8;
typedef __attribute__((ext_vector_type(4))) float f32x4;

__device__ __forceinline__ float bf2f(unsigned short u) {
  unsigned int x = ((unsigned int)u) << 16;
  return __builtin_bit_cast(float, x);
}
__device__ __forceinline__ unsigned short f2bf(float f) {
  unsigned int x = __builtin_bit_cast(unsigned int, f);
  x = x + 0x7fffu + ((x >> 16) & 1u);
  return (unsigned short)(x >> 16);
}

#define GLOAD16(g, l)                                                          \
  __builtin_amdgcn_global_load_lds(                                            \
      (const __attribute__((address_space(1))) unsigned int*)(g),              \
      (__attribute__((address_space(3))) unsigned int*)(l), 16, 0, 0)

// ============ prep mega-kernel: casts + transpose + bias fusions ===========
// Block ranges (256 threads each):
//  [0,4096)      cast x -> xbf            (8 elems/thread)
//  [4096,4608)   cast Wq -> wqk[0:1M)
//  [4608,5120)   cast Wk -> wqk[1M:2M)
//  [5120,5632)   cast Wo -> wobf
//  [5632,6656)   transpose-cast Wv -> wvT
//  [6656,6912)   bias_fuse: bpr = Wo.bv + bo
//  [6912,6944)   Srow = 0
__global__ __launch_bounds__(256) void prep(
    const float* __restrict__ x, const float* __restrict__ Wq,
    const float* __restrict__ bq, const float* __restrict__ Wk,
    const float* __restrict__ Wv, const float* __restrict__ bv,
    const float* __restrict__ Wo, const float* __restrict__ bo,
    unsigned short* __restrict__ xbf, unsigned short* __restrict__ wqk,
    unsigned short* __restrict__ wobf, unsigned short* __restrict__ wvT,
    float* __restrict__ bpr, float* __restrict__ Srow) {
  const int blk = blockIdx.x;
  const int tid = threadIdx.x;
  if (blk < 4096) {  // x cast
    const long long i = ((long long)blk * 256 + tid) * 8;
    f32x4 a = *(const f32x4*)(x + i);
    f32x4 b = *(const f32x4*)(x + i + 4);
    ushort8 o;
    o[0] = f2bf(a[0]); o[1] = f2bf(a[1]); o[2] = f2bf(a[2]); o[3] = f2bf(a[3]);
    o[4] = f2bf(b[0]); o[5] = f2bf(b[1]); o[6] = f2bf(b[2]); o[7] = f2bf(b[3]);
    *(ushort8*)(xbf + i) = o;
  } else if (blk < 5632) {  // weight casts
    const float* src = (blk < 4608) ? Wq : (blk < 5120) ? Wk : Wo;
    unsigned short* dst =
        (blk < 4608) ? wqk : (blk < 5120) ? (wqk + HID * HID) : wobf;
    const int b = (blk - 4096) & 511;
    const int i = (b * 256 + tid) * 8;
    f32x4 a = *(const f32x4*)(src + i);
    f32x4 c = *(const f32x4*)(src + i + 4);
    ushort8 o;
    o[0] = f2bf(a[0]); o[1] = f2bf(a[1]); o[2] = f2bf(a[2]); o[3] = f2bf(a[3]);
    o[4] = f2bf(c[0]); o[5] = f2bf(c[1]); o[6] = f2bf(c[2]); o[7] = f2bf(c[3]);
    *(ushort8*)(dst + i) = o;
  } else if (blk < 6656) {  // Wv transpose-cast
    __shared__ float t[32][33];
    const int b = blk - 5632;
    const int bx = (b & 31) * 32, by = (b >> 5) * 32;
    const int tx = tid & 31, ty = tid >> 5;  // 32 x 8
#pragma unroll
    for (int i = 0; i < 4; ++i)
      t[ty + i * 8][tx] = Wv[(by + ty + i * 8) * 1024 + bx + tx];
    __syncthreads();
#pragma unroll
    for (int i = 0; i < 4; ++i)
      wvT[(bx + ty + i * 8) * 1024 + by + tx] = f2bf(t[tx][ty + i * 8]);
  } else if (blk < 6912) {  // bias_fuse
    const int row = (blk - 6656) * 4 + (tid >> 6);
    const int lane = tid & 63;
    float s = 0.f;
    for (int k = lane; k < 1024; k += 64) s += Wo[row * 1024 + k] * bv[k];
#pragma unroll
    for (int off = 32; off >= 1; off >>= 1) s += __shfl_xor(s, off, 64);
    if (lane == 0) bpr[row] = s + bo[row];
  } else {  // Srow zero
    Srow[(blk - 6912) * 256 + tid] = 0.0f;
  }
}

// ========== 256 x BN 2-phase NT GEMM (BK=64, 8 waves) — r12 engine =========
// Used only for wov (tiny). BIAS_MODE: 0 none.
template <int BN, int OUT_F32, int BIAS_MODE>
__global__ __launch_bounds__(512, 2) void gemm2p(
    const unsigned short* __restrict__ A, const unsigned short* __restrict__ B,
    void* __restrict__ Cv, const float* __restrict__ bias,
    const float* __restrict__ bias2, int K, int lda, int ldb, int ldc,
    long long bsA, long long bsB, long long bsC, float alpha) {
  static_assert(BN == 256 || BN == 128, "BN");
  constexpr int WMW = (BN == 256) ? 2 : 4;
  constexpr int WNW = 8 / WMW;
  constexpr int MI = (256 / WMW) / 16;
  constexpr int GB = BN / 64;
  constexpr int WROWS = 256 / WMW;

  __shared__ unsigned short lA[2][256 * 64];
  __shared__ unsigned short lB[2][BN * 64];

  const int tid = threadIdx.x;
  const int lane = tid & 63, wid = tid >> 6;
  const int fr = lane & 15, fq = lane >> 4;
  const int wm = wid / WNW, wn = wid % WNW;

  const int nx = gridDim.x;
  const int nwg = nx * gridDim.y;
  int f = blockIdx.y * nx + blockIdx.x;
  f = (f & 7) * (nwg >> 3) + (f >> 3);
  const int bx = f % nx, by = f / nx;
  const int bz = blockIdx.z;

  const unsigned short* Ag = A + bz * bsA + (long long)by * 256 * lda;
  const unsigned short* Bg = B + bz * bsB + (long long)bx * BN * ldb;
  const int NT = K >> 6;

  const int srow = tid >> 3;
  const int gcol = 8 * ((tid & 7) ^ ((tid >> 3) & 7));
  const int ldst = wid * 512;

  auto stage = [&](int t) {
    const int b = t & 1;
#pragma unroll
    for (int c = 0; c < 4; ++c)
      GLOAD16(Ag + (long long)(c * 64 + srow) * lda + t * 64 + gcol,
              &lA[b][c * 4096 + ldst]);
#pragma unroll
    for (int c = 0; c < GB; ++c)
      GLOAD16(Bg + (long long)(c * 64 + srow) * ldb + t * 64 + gcol,
              &lB[b][c * 4096 + ldst]);
  };

  const int rxor = fr & 7;
  f32x4 acc[MI][4] = {};

  auto phase = [&](const unsigned short* pa, const unsigned short* pb,
                   int kk) {
    short8 av[MI], bw[4];
    const int slot = ((kk << 2) | fq) ^ rxor;
#pragma unroll
    for (int i = 0; i < MI; ++i)
      av[i] = *(const short8*)(pa + (wm * WROWS + i * 16 + fr) * 64 + slot * 8);
#pragma unroll
    for (int n = 0; n < 4; ++n)
      bw[n] = *(const short8*)(pb + (wn * 64 + n * 16 + fr) * 64 + slot * 8);
    asm volatile("s_waitcnt lgkmcnt(0)" ::: "memory");
    __builtin_amdgcn_sched_barrier(0);
    __builtin_amdgcn_s_setprio(1);
#pragma unroll
    for (int i = 0; i < MI; ++i)
#pragma unroll
      for (int n = 0; n < 4; ++n)
        acc[i][n] = __builtin_amdgcn_mfma_f32_16x16x32_bf16(av[i], bw[n],
                                                            acc[i][n], 0, 0, 0);
    __builtin_amdgcn_s_setprio(0);
  };

  stage(0);
  asm volatile("s_waitcnt vmcnt(0)" ::: "memory");
  __builtin_amdgcn_s_barrier();

  for (int t = 0; t < NT; ++t) {
    if (t + 1 < NT) stage(t + 1);
    const unsigned short* pa = lA[t & 1];
    const unsigned short* pb = lB[t & 1];
    phase(pa, pb, 0);
    phase(pa, pb, 1);
    asm volatile("s_waitcnt vmcnt(0)" ::: "memory");
    __builtin_amdgcn_s_barrier();
  }

  const long long cb0 = (long long)bz * bsC;
#pragma unroll
  for (int i = 0; i < MI; ++i)
#pragma unroll
    for (int j = 0; j < 4; ++j) {
      const int row = wm * WROWS + i * 16 + fq * 4 + j;
#pragma unroll
      for (int n = 0; n < 4; ++n) {
        const int col = bx * BN + wn * 64 + n * 16 + fr;
        float v = acc[i][n][j] * alpha;
        if (BIAS_MODE == 1) v += bias[col];
        if (BIAS_MODE == 3) v += (col < 1024) ? bias[col] : bias2[col - 1024];
        const long long idx = cb0 + (long long)(by * 256 + row) * ldc + col;
        if (OUT_F32)
          ((float*)Cv)[idx] = v;
        else
          ((unsigned short*)Cv)[idx] = f2bf(v);
      }
    }
}

// ======== gemm_s core (r14 engine, 256x128, BK=32, 48KB LDS) as device fn ==
// Runtime bias_mode (0 none, 1 bias[col], 3 col<1024?bias:bias2), bf16 out,
// no EPI. Caller provides LDS and the flattened (pre-swizzle) block id.
__device__ __forceinline__ void gemm_core(
    const unsigned short* __restrict__ A0, const unsigned short* __restrict__ B0,
    unsigned short* __restrict__ C, const float* __restrict__ bias,
    const float* __restrict__ bias2, int bias_mode, int K, int lda, int ldb,
    int ldc, float alpha, int bid, int nx, int nwg,
    unsigned short (&lA)[2][256 * 32], unsigned short (&lB)[2][128 * 32]) {
  const int tid = threadIdx.x;
  const int lane = tid & 63, wid = tid >> 6;
  const int fr = lane & 15, fq = lane >> 4;
  const int wm = wid >> 1, wn = wid & 1;

  int f = (bid & 7) * (nwg >> 3) + (bid >> 3);
  const int bx = f % nx, by = f / nx;

  const unsigned short* Ag = A0 + (long long)by * 256 * lda;
  const unsigned short* Bg = B0 + (long long)bx * 128 * ldb;
  const int NT = K >> 5;

  const int srow = tid >> 2;
  const int scol = 8 * ((tid & 3) ^ ((tid >> 3) & 3));
  const int ldst = wid * 512;

  auto stage = [&](int t) {
    const int b = t & 1;
    GLOAD16(Ag + (long long)srow * lda + t * 32 + scol, &lA[b][ldst]);
    GLOAD16(Ag + (long long)(128 + srow) * lda + t * 32 + scol,
            &lA[b][4096 + ldst]);
    GLOAD16(Bg + (long long)srow * ldb + t * 32 + scol, &lB[b][ldst]);
  };

  const int xm = ((fr >> 1) & 3) << 3;
  f32x4 acc[4][4] = {};

  stage(0);
  asm volatile("s_waitcnt vmcnt(0)" ::: "memory");
  __builtin_amdgcn_s_barrier();

  for (int t = 0; t < NT; ++t) {
    if (t + 1 < NT) stage(t + 1);
    const unsigned short* pa = lA[t & 1];
    const unsigned short* pb = lB[t & 1];
    short8 av[4], bw[4];
#pragma unroll
    for (int i = 0; i < 4; ++i)
      av[i] = *(const short8*)(pa +
                               (((wm * 64 + i * 16 + fr) * 32 + fq * 8) ^ xm));
#pragma unroll
    for (int n = 0; n < 4; ++n)
      bw[n] = *(const short8*)(pb +
                               (((wn * 64 + n * 16 + fr) * 32 + fq * 8) ^ xm));
    asm volatile("s_waitcnt lgkmcnt(0)" ::: "memory");
    __builtin_amdgcn_sched_barrier(0);
    __builtin_amdgcn_s_setprio(1);
#pragma unroll
    for (int i = 0; i < 4; ++i)
#pragma unroll
      for (int n = 0; n < 4; ++n)
        acc[i][n] = __builtin_amdgcn_mfma_f32_16x16x32_bf16(av[i], bw[n],
                                                            acc[i][n], 0, 0, 0);
    __builtin_amdgcn_s_setprio(0);
    asm volatile("s_waitcnt vmcnt(0)" ::: "memory");
    __builtin_amdgcn_s_barrier();
  }

#pragma unroll
  for (int i = 0; i < 4; ++i)
#pragma unroll
    for (int j = 0; j < 4; ++j) {
      const int row = wm * 64 + i * 16 + fq * 4 + j;
#pragma unroll
      for (int n = 0; n < 4; ++n) {
        const int col = bx * 128 + wn * 64 + n * 16 + fr;
        float v = acc[i][n][j] * alpha;
        if (bias_mode == 1) v += bias[col];
        else if (bias_mode == 3) v += (col < 1024) ? bias[col] : bias2[col - 1024];
        C[(long long)(by * 256 + row) * ldc + col] = f2bf(v);
      }
    }
}

// ======== dual launch: QKproj (blocks 0-511) || VWoT (blocks 512-767) ======
__global__ __launch_bounds__(512, 4) void gemm_dual(
    const unsigned short* __restrict__ xbf, const unsigned short* __restrict__ wqk,
    const unsigned short* __restrict__ wov, unsigned short* __restrict__ QKb,
    unsigned short* __restrict__ VWoT, const float* __restrict__ bq,
    const float* __restrict__ bk) {
  __shared__ unsigned short lA[2][256 * 32];
  __shared__ unsigned short lB[2][128 * 32];
  const int bid = blockIdx.x;
  if (bid < 512) {
    // [Q|K] = x @ [Wq;Wk]^T + [bq;bk] : [8192,2048], tiles 16x32
    gemm_core(xbf, wqk, QKb, bq, bk, 3, HID, HID, HID, 2048, 1.0f, bid, 16,
              512, lA, lB);
  } else {
    // VWoT = wov @ x^T : [1024,8192], tiles 64x4
    gemm_core(wov, xbf, VWoT, nullptr, nullptr, 0, HID, HID, HID, BS, 1.0f,
              bid - 512, 64, 256, lA, lB);
  }
}

// ========== standalone gemm_s (r14): for exp-QKT and PV =====================
// BIAS_MODE: 0 none, 1 bias[col].
// EPI: 1 exp(v)+rowsum->Srow atomics, 2 scale by 1/Srow (pre-bias).
template <int OUT_F32, int BIAS_MODE, int EPI>
__global__ __launch_bounds__(512, 4) void gemm_s(
    const unsigned short* __restrict__ A, const unsigned short* __restrict__ B,
    void* __restrict__ Cv, const float* __restrict__ bias,
    float* __restrict__ Srow, int K, int lda, int ldb, int ldc, long long bsA,
    long long bsB, long long bsC, float alpha) {
  __shared__ unsigned short lA[2][256 * 32];
  __shared__ unsigned short lB[2][128 * 32];

  const int tid = threadIdx.x;
  const int lane = tid & 63, wid = tid >> 6;
  const int fr = lane & 15, fq = lane >> 4;
  const int wm = wid >> 1, wn = wid & 1;

  const int nx = gridDim.x;
  const int nwg = nx * gridDim.y;
  int f = blockIdx.y * nx + blockIdx.x;
  f = (f & 7) * (nwg >> 3) + (f >> 3);
  const int bx = f % nx, by = f / nx;
  const int bz = blockIdx.z;

  const unsigned short* Ag = A + bz * bsA + (long long)by * 256 * lda;
  const unsigned short* Bg = B + bz * bsB + (long long)bx * 128 * ldb;
  const int NT = K >> 5;

  const int srow = tid >> 2;
  const int scol = 8 * ((tid & 3) ^ ((tid >> 3) & 3));
  const int ldst = wid * 512;

  auto stage = [&](int t) {
    const int b = t & 1;
    GLOAD16(Ag + (long long)srow * lda + t * 32 + scol, &lA[b][ldst]);
    GLOAD16(Ag + (long long)(128 + srow) * lda + t * 32 + scol,
            &lA[b][4096 + ldst]);
    GLOAD16(Bg + (long long)srow * ldb + t * 32 + scol, &lB[b][ldst]);
  };

  const int xm = ((fr >> 1) & 3) << 3;
  f32x4 acc[4][4] = {};

  stage(0);
  asm volatile("s_waitcnt vmcnt(0)" ::: "memory");
  __builtin_amdgcn_s_barrier();

  for (int t = 0; t < NT; ++t) {
    if (t + 1 < NT) stage(t + 1);
    const unsigned short* pa = lA[t & 1];
    const unsigned short* pb = lB[t & 1];
    short8 av[4], bw[4];
#pragma unroll
    for (int i = 0; i < 4; ++i)
      av[i] = *(const short8*)(pa +
                               (((wm * 64 + i * 16 + fr) * 32 + fq * 8) ^ xm));
#pragma unroll
    for (int n = 0; n < 4; ++n)
      bw[n] = *(const short8*)(pb +
                               (((wn * 64 + n * 16 + fr) * 32 + fq * 8) ^ xm));
    asm volatile("s_waitcnt lgkmcnt(0)" ::: "memory");
    __builtin_amdgcn_sched_barrier(0);
    __builtin_amdgcn_s_setprio(1);
#pragma unroll
    for (int i = 0; i < 4; ++i)
#pragma unroll
      for (int n = 0; n < 4; ++n)
        acc[i][n] = __builtin_amdgcn_mfma_f32_16x16x32_bf16(av[i], bw[n],
                                                            acc[i][n], 0, 0, 0);
    __builtin_amdgcn_s_setprio(0);
    asm volatile("s_waitcnt vmcnt(0)" ::: "memory");
    __builtin_amdgcn_s_barrier();
  }

  const long long cb0 = (long long)bz * bsC;
  float* sredf = (float*)lA;  // [256][2] row-sum scratch (EPI==1)
#pragma unroll
  for (int i = 0; i < 4; ++i)
#pragma unroll
    for (int j = 0; j < 4; ++j) {
      const int row = wm * 64 + i * 16 + fq * 4 + j;
      float inv = 1.0f;
      if (EPI == 2) inv = 1.0f / Srow[(long long)bz * SEQ + by * 256 + row];
      float rps = 0.0f;
#pragma unroll
      for (int n = 0; n < 4; ++n) {
        const int col = bx * 128 + wn * 64 + n * 16 + fr;
        float v = acc[i][n][j] * alpha;
        if (EPI == 1) { v = __expf(v); rps += v; }
        if (EPI == 2) v *= inv;
        if (BIAS_MODE == 1) v += bias[col];
        const long long idx = cb0 + (long long)(by * 256 + row) * ldc + col;
        if (OUT_F32)
          ((float*)Cv)[idx] = v;
        else
          ((unsigned short*)Cv)[idx] = f2bf(v);
      }
      if (EPI == 1) {
        rps += __shfl_xor(rps, 1, 64);
        rps += __shfl_xor(rps, 2, 64);
        rps += __shfl_xor(rps, 4, 64);
        rps += __shfl_xor(rps, 8, 64);
        if (fr == 0) sredf[row * 2 + wn] = rps;
      }
    }
  if (EPI == 1) {
    __syncthreads();
    if (tid < 256) {
      const float s2 = sredf[tid * 2] + sredf[tid * 2 + 1];
      atomicAdd(Srow + (long long)bz * SEQ + by * 256 + tid, s2);
    }
  }
}

extern "C" void kernel_launch(void* const* d_in, const int* in_sizes, int n_in,
                              void* d_out, int out_size, void* d_ws,
                              size_t ws_size, hipStream_t stream) {
  (void)in_sizes; (void)n_in; (void)out_size; (void)ws_size;
  const float* x = (const float*)d_in[0];
  const float* Wq = (const float*)d_in[1];
  const float* bq = (const float*)d_in[2];
  const float* Wk = (const float*)d_in[3];
  const float* bk = (const float*)d_in[4];
  const float* Wv = (const float*)d_in[5];
  const float* bv = (const float*)d_in[6];
  const float* Wo = (const float*)d_in[7];
  const float* bo = (const float*)d_in[8];
  float* out = (float*)d_out;

  char* ws = (char*)d_ws;
  unsigned short* xbf  = (unsigned short*)(ws + 0);         // 16 MiB
  unsigned short* wqk  = (unsigned short*)(ws + 16777216);  // 4 MiB [2048][1024]
  unsigned short* wobf = (unsigned short*)(ws + 20971520);  // 2 MiB
  unsigned short* wvT  = (unsigned short*)(ws + 23068672);  // 2 MiB (Wv^T)
  unsigned short* wov  = (unsigned short*)(ws + 25165824);  // 2 MiB (Wo.Wv)
  float*          bpr  = (float*)        (ws + 27262976);   // 4 KiB (Wo.bv+bo)
  float*          Srow = (float*)        (ws + 28311552);   // 32 KiB rowsums
  unsigned short* VWoT = (unsigned short*)(ws + 33554432);  // 16 MiB [1024][8192]
  unsigned short* QKb  = (unsigned short*)(ws + 50331648);  // 32 MiB [8192][2048]
  unsigned short* P    = (unsigned short*)(ws + 83886080);  // 32 MiB [4][2048][2048]

  // 1) all prep in one launch (casts, Wv transpose, bias fusion, Srow=0)
  prep<<<6944, 256, 0, stream>>>(x, Wq, bq, Wk, Wv, bv, Wo, bo, xbf, wqk,
                                 wobf, wvT, bpr, Srow);
  // 2) wov = Wo @ Wv : [1024,1024] (tiny)
  gemm2p<128, 0, 0><<<dim3(8, 4, 1), 512, 0, stream>>>(
      wobf, wvT, wov, nullptr, nullptr, HID, HID, HID, HID, 0, 0, 0, 1.0f);
  // 3) QKproj || VWoT in one 768-block launch (2 blocks/CU co-residency)
  gemm_dual<<<768, 512, 0, stream>>>(xbf, wqk, wov, QKb, VWoT, bq, bk);
  // 4) P = exp(Q @ K^T / 32) per batch + rowsums : [4][2048][2048]
  gemm_s<0, 0, 1><<<dim3(16, 8, NB), 512, 0, stream>>>(
      QKb, QKb + 1024, P, nullptr, Srow, HID, 2048, 2048, SEQ,
      (long long)SEQ * 2048, (long long)SEQ * 2048, (long long)SEQ * SEQ,
      0.03125f);
  // 5) out = (P @ VWoT^T) / Srow + b' : [8192,1024] fp32
  gemm_s<1, 1, 2><<<dim3(8, 8, NB), 512, 0, stream>>>(
      P, VWoT, out, bpr, Srow, SEQ, SEQ, BS, HID, (long long)SEQ * SEQ,
      (long long)SEQ, (long long)SEQ * HID, 1.0f);
}